// Round 13
// baseline (25.082 us; speedup 1.0000x reference)
//
#include <hip/hip_runtime.h>

#define NQ 6
#define NL 6
#define TSTRIDE 148   // words per sample trig row: 36 gates * 4 + 4 pad

// R13 = R12 (passed, 24.8us) with lane^8 moved BACK to VALU DPP (ROW_ROR:8,
// 1 op — validated R9-R11); lane^4 stays on the DS pipe (ds_swizzle 0x101F,
// validated R12; VALU form costs 2 DPP). Pipe-balance: VALU ~8.6us, DS ~7us.
// Everything else byte-identical to R12 (validated R8..R12).
// 16 lanes per sample, 4 samples/wave. amplitude k = (b5..b0):
//   b5..b2 <-> L bits 3..0 (L = lane & 15); b1 = pair p; b0 = half h (.x/.y)

typedef float v2f __attribute__((ext_vector_type(2)));

template<int CTRL>
__device__ __forceinline__ float dppf(float x) {
    return __builtin_bit_cast(float,
        __builtin_amdgcn_update_dpp(0, __builtin_bit_cast(int, x), CTRL, 0xF, 0xF, true));
}
// masked conditional DPP: enabled banks get quad_perm<CTRL>(src), others keep old
template<int CTRL, int BANK>
__device__ __forceinline__ float dppsel(float old, float src) {
    return __builtin_bit_cast(float,
        __builtin_amdgcn_update_dpp(__builtin_bit_cast(int, old),
                                    __builtin_bit_cast(int, src),
                                    CTRL, 0xF, BANK, false));
}
// DS-pipe lane xor shuffle (BitMode: offset = (xor<<10) | 0x1F)
template<int OFF>
__device__ __forceinline__ float swzf(float x) {
    return __builtin_bit_cast(float,
        __builtin_amdgcn_ds_swizzle(__builtin_bit_cast(int, x), OFF));
}
__device__ __forceinline__ float sx1(float x) { return dppf<0xB1>(x); }    // lane^1 (VALU)
__device__ __forceinline__ float sx2(float x) { return dppf<0x4E>(x); }    // lane^2 (VALU)
__device__ __forceinline__ float sx4(float x) { return swzf<0x101F>(x); }  // lane^4 (DS)
__device__ __forceinline__ float sx8(float x) { return dppf<0x128>(x); }   // lane^8 (VALU, ROW_ROR:8)

__device__ __forceinline__ v2f fma2(v2f a, v2f b, v2f c) {
    return __builtin_elementwise_fma(a, b, c);
}
__device__ __forceinline__ v2f swap2(v2f a) { return __builtin_shufflevector(a, a, 1, 0); }

template<int M>
__device__ __forceinline__ v2f shuf2(v2f a) {
    if constexpr (M == 1) return v2f{sx1(a.x), sx1(a.y)};
    else if constexpr (M == 2) return v2f{sx2(a.x), sx2(a.y)};
    else if constexpr (M == 4) return v2f{sx4(a.x), sx4(a.y)};
    else return v2f{sx8(a.x), sx8(a.y)};
}

// ---- RZ(q): diagonal, no communication ----
template<int Q>
__device__ __forceinline__ void rz2(v2f (&re)[2], v2f (&im)[2], float c, float s, int L) {
    const v2f C = {c, c};
    if constexpr (Q < 4) {
        const int lm = 8 >> Q;
        const float s2 = (L & lm) ? s : -s;
        const v2f S = {s2, s2};
        #pragma unroll
        for (int p = 0; p < 2; ++p) {
            const v2f nr = fma2(re[p], C, -(im[p] * S));
            im[p] = fma2(re[p], S, im[p] * C);
            re[p] = nr;
        }
    } else if constexpr (Q == 4) {
        const v2f Sn = {-s, -s}, Sp = {s, s};
        { const v2f nr = fma2(re[0], C, -(im[0] * Sn));
          im[0] = fma2(re[0], Sn, im[0] * C); re[0] = nr; }
        { const v2f nr = fma2(re[1], C, -(im[1] * Sp));
          im[1] = fma2(re[1], Sp, im[1] * C); re[1] = nr; }
    } else {
        const v2f S = {-s, s};
        #pragma unroll
        for (int p = 0; p < 2; ++p) {
            const v2f nr = fma2(re[p], C, -(im[p] * S));
            im[p] = fma2(re[p], S, im[p] * C);
            re[p] = nr;
        }
    }
}

// ---- RY(q) ----
template<int Q>
__device__ __forceinline__ void ry2(v2f (&re)[2], v2f (&im)[2], float c, float s, int L) {
    const v2f C = {c, c};
    if constexpr (Q < 4) {
        const int lm = 8 >> Q;
        const float sg = (L & lm) ? s : -s;
        const v2f SG = {sg, sg};
        #pragma unroll
        for (int p = 0; p < 2; ++p) {
            const v2f ore = shuf2<(8 >> Q)>(re[p]);
            const v2f oim = shuf2<(8 >> Q)>(im[p]);
            re[p] = fma2(C, re[p], SG * ore);
            im[p] = fma2(C, im[p], SG * oim);
        }
    } else if constexpr (Q == 4) {
        const v2f S = {s, s};
        const v2f a0r = re[0], a0i = im[0], a1r = re[1], a1i = im[1];
        re[0] = fma2(C, a0r, -(S * a1r));
        im[0] = fma2(C, a0i, -(S * a1i));
        re[1] = fma2(S, a0r, C * a1r);
        im[1] = fma2(S, a0i, C * a1i);
    } else {
        const v2f SM = {-s, s};
        #pragma unroll
        for (int p = 0; p < 2; ++p) {
            re[p] = fma2(C, re[p], SM * swap2(re[p]));
            im[p] = fma2(C, im[p], SM * swap2(im[p]));
        }
    }
}

__device__ __forceinline__ void cnot_block(v2f (&re)[2], v2f (&im)[2], int L) {
    // CNOT(0,1): ctrl b5 (L&8 -> banks 2,3). tgt b4 (lane^4 = xor7 o xor3).
    // Stage1 (xor7) all lanes; stage2 (quad_perm 0x1B = xor3) masked to banks 2,3
    // with old = original value -> conditional move. (VALU, validated R11/R12)
    #pragma unroll
    for (int p = 0; p < 2; ++p) {
        const float t0 = dppf<0x141>(re[p].x), t1 = dppf<0x141>(re[p].y);
        const float u0 = dppf<0x141>(im[p].x), u1 = dppf<0x141>(im[p].y);
        re[p].x = dppsel<0x1B, 0xC>(re[p].x, t0);
        re[p].y = dppsel<0x1B, 0xC>(re[p].y, t1);
        im[p].x = dppsel<0x1B, 0xC>(im[p].x, u0);
        im[p].y = dppsel<0x1B, 0xC>(im[p].y, u1);
    }
    // CNOT(1,2): ctrl b4 (L&4 -> banks 1,3), tgt b3 (lane^2 = quad_perm 0x4E).
    #pragma unroll
    for (int p = 0; p < 2; ++p) {
        re[p].x = dppsel<0x4E, 0xA>(re[p].x, re[p].x);
        re[p].y = dppsel<0x4E, 0xA>(re[p].y, re[p].y);
        im[p].x = dppsel<0x4E, 0xA>(im[p].x, im[p].x);
        im[p].y = dppsel<0x4E, 0xA>(im[p].y, im[p].y);
    }
    // CNOT(2,3): ctrl b3 (L&2), tgt b2 (lane^1): quad_perm [0,1,3,2] = 0xB4
    #pragma unroll
    for (int p = 0; p < 2; ++p) {
        re[p].x = dppf<0xB4>(re[p].x);
        re[p].y = dppf<0xB4>(re[p].y);
        im[p].x = dppf<0xB4>(im[p].x);
        im[p].y = dppf<0xB4>(im[p].y);
    }
    // CNOT(3,4): ctrl b2 (L&1), tgt b1: conditional pair swap
    const bool c34 = (L & 1) != 0;
    {
        const v2f ar = re[0], ai = im[0], br = re[1], bi = im[1];
        re[0] = c34 ? br : ar;  im[0] = c34 ? bi : ai;
        re[1] = c34 ? ar : br;  im[1] = c34 ? ai : bi;
    }
    // CNOT(4,5): ctrl b1 (pair 1), tgt b0: unconditional half-swap of pair 1
    re[1] = swap2(re[1]);  im[1] = swap2(im[1]);
    // CNOT(5,0): ctrl b0 (.y halves), tgt b5: lane^8 on .y only (VALU DPP)
    #pragma unroll
    for (int p = 0; p < 2; ++p) {
        re[p].y = sx8(re[p].y);
        im[p].y = sx8(im[p].y);
    }
}

__global__ __launch_bounds__(256, 8) void qsim_kernel(
    const float* __restrict__ x,
    const float* __restrict__ w,
    float* __restrict__ out,
    int batch)
{
    __shared__ float tbl[16 * TSTRIDE];
    __shared__ float outbuf[4][24];

    const int tid   = threadIdx.x;
    const int wavei = tid >> 6;
    const int lane  = tid & 63;
    const int L     = lane & 15;          // position within sample
    const int sw    = lane >> 4;          // sample within wave 0..3
    const int S     = tid >> 4;           // sample within block 0..15
    const int b     = blockIdx.x * 16 + S;
    if (b >= batch) return;               // exact for B=32768 (never divergent)

    float* T = &tbl[S * TSTRIDE];

    // ---- wave-local trig fill: 72 angles/sample, <=5 per lane ----
    {
        const float* wp = w + (size_t)b * (2 * NQ * NL);
        #pragma unroll
        for (int j = 0; j < 5; ++j) {
            const int A = L + 16 * j;                     // angle id
            if (A < 72) {
                float s, c;
                __sincosf(wp[A] * 0.5f, &s, &c);
                const int word = (A >> 1) * 4 + (A & 1) * 2;  // gate*4 + {0:z,2:y}
                T[word]     = c;
                T[word + 1] = s;
            }
        }
    }

    // ---- encode angles via half-angle identities (4 live scalars) ----
    const float x0 = x[b * 3 + 0];
    const float x1 = x[b * 3 + 1];
    const float x2 = x[b * 3 + 2];
    const float z  = fminf(1.f, fmaxf(-1.f, x2));
    const float ct = sqrtf(0.5f * (1.f + z));             // cos(theta/2)
    const float st = sqrtf(0.5f * (1.f - z));             // sin(theta/2)
    const float rr = sqrtf(x0 * x0 + x1 * x1) + 1e-30f;
    const float cphi = x0 / rr;
    const float cp = sqrtf(fmaxf(0.f, 0.5f * (1.f + cphi)));
    float sp       = sqrtf(fmaxf(0.f, 0.5f * (1.f - cphi)));
    sp = (x1 < 0.f) ? -sp : sp;   // 2pi wrap & sign = global phase, cancels

    // ---- |0...0> then gate-based encode: RY(theta), RZ(phi) per qubit ----
    v2f re[2], im[2];
    re[0] = v2f{(L == 0) ? 1.f : 0.f, 0.f};
    re[1] = v2f{0.f, 0.f};
    im[0] = v2f{0.f, 0.f};
    im[1] = v2f{0.f, 0.f};

    ry2<0>(re, im, ct, st, L);  rz2<0>(re, im, cp, sp, L);
    ry2<1>(re, im, ct, st, L);  rz2<1>(re, im, cp, sp, L);
    ry2<2>(re, im, ct, st, L);  rz2<2>(re, im, cp, sp, L);
    ry2<3>(re, im, ct, st, L);  rz2<3>(re, im, cp, sp, L);
    ry2<4>(re, im, ct, st, L);  rz2<4>(re, im, cp, sp, L);
    ry2<5>(re, im, ct, st, L);  rz2<5>(re, im, cp, sp, L);

    // ---- variational layers: rolled loop (R10-validated) ----
    #pragma unroll 1
    for (int l = 0; l < NL; ++l) {
        const float* Tl = &T[l * 24];
        const float4 c0 = *(const float4*)&Tl[ 0];
        const float4 c1 = *(const float4*)&Tl[ 4];
        const float4 c2 = *(const float4*)&Tl[ 8];
        const float4 c3 = *(const float4*)&Tl[12];
        const float4 c4 = *(const float4*)&Tl[16];
        const float4 c5 = *(const float4*)&Tl[20];
        rz2<0>(re, im, c0.x, c0.y, L);  ry2<0>(re, im, c0.z, c0.w, L);
        rz2<1>(re, im, c1.x, c1.y, L);  ry2<1>(re, im, c1.z, c1.w, L);
        rz2<2>(re, im, c2.x, c2.y, L);  ry2<2>(re, im, c2.z, c2.w, L);
        rz2<3>(re, im, c3.x, c3.y, L);  ry2<3>(re, im, c3.z, c3.w, L);
        rz2<4>(re, im, c4.x, c4.y, L);  ry2<4>(re, im, c4.z, c4.w, L);
        rz2<5>(re, im, c5.x, c5.y, L);  ry2<5>(re, im, c5.z, c5.w, L);
        if (l < NL - 1) cnot_block(re, im, L);   // uniform branch
    }
    // final CNOT block folded into readout remap (validated R3..R12)

    // ---- probs -> FWHT (2 register stages + 4 lane stages) ----
    v2f v[2];
    v[0] = fma2(re[0], re[0], im[0] * im[0]);
    v[1] = fma2(re[1], re[1], im[1] * im[1]);
    {   // amp bit1 (pair)
        const v2f a = v[0], bb = v[1];
        v[0] = a + bb; v[1] = a - bb;
    }
    {   // amp bit0 (half)
        const v2f PM = {1.f, -1.f};
        v[0] = fma2(PM, v[0], swap2(v[0]));
        v[1] = fma2(PM, v[1], swap2(v[1]));
    }
    {   // amp bit2 <-> L bit0
        const float sg = (L & 1) ? -1.f : 1.f;  const v2f SG = {sg, sg};
        v[0] = fma2(SG, v[0], shuf2<1>(v[0]));
        v[1] = fma2(SG, v[1], shuf2<1>(v[1]));
    }
    {   // amp bit3 <-> L bit1
        const float sg = (L & 2) ? -1.f : 1.f;  const v2f SG = {sg, sg};
        v[0] = fma2(SG, v[0], shuf2<2>(v[0]));
        v[1] = fma2(SG, v[1], shuf2<2>(v[1]));
    }
    {   // amp bit4 <-> L bit2 (DS pipe)
        const float sg = (L & 4) ? -1.f : 1.f;  const v2f SG = {sg, sg};
        v[0] = fma2(SG, v[0], shuf2<4>(v[0]));
        v[1] = fma2(SG, v[1], shuf2<4>(v[1]));
    }
    {   // amp bit5 <-> L bit3 (VALU DPP)
        const float sg = (L & 8) ? -1.f : 1.f;  const v2f SG = {sg, sg};
        v[0] = fma2(SG, v[0], shuf2<8>(v[0]));
        v[1] = fma2(SG, v[1], shuf2<8>(v[1]));
    }
    // lane L, pair p, half h holds WHT[L*4 + 2p + h]

    // ---- readout (skipped final-CNOT remap, validated): e = {31,48,56,60,62,63} ----
    if (L == 7)  outbuf[wavei][sw * 6 + 0] = v[1].y;   // e=31
    if (L == 12) outbuf[wavei][sw * 6 + 1] = v[0].x;   // e=48
    if (L == 14) outbuf[wavei][sw * 6 + 2] = v[0].x;   // e=56
    if (L == 15) {
        outbuf[wavei][sw * 6 + 3] = v[0].x;            // e=60
        outbuf[wavei][sw * 6 + 4] = v[1].x;            // e=62
        outbuf[wavei][sw * 6 + 5] = v[1].y;            // e=63
    }
    if (lane < 24) {
        const float ev = outbuf[wavei][lane];
        const long long oidx = (long long)(blockIdx.x * 16 + wavei * 4) * 6 + lane;
        if (oidx < (long long)batch * 6)
            out[oidx] = 1.f / (1.f + __expf(-ev));
    }
}

extern "C" void kernel_launch(void* const* d_in, const int* in_sizes, int n_in,
                              void* d_out, int out_size, void* d_ws, size_t ws_size,
                              hipStream_t stream) {
    const float* x = (const float*)d_in[0];
    const float* w = (const float*)d_in[1];
    float* out = (float*)d_out;
    const int batch = in_sizes[0] / 3;   // B = 32768

    const int threads = 256;             // 4 waves = 16 samples per block
    const int blocks = (batch + 15) / 16;
    qsim_kernel<<<blocks, threads, 0, stream>>>(x, w, out, batch);
}

// Round 14
// 24.640 us; speedup vs baseline: 1.0179x; 1.0179x over previous
//
#include <hip/hip_runtime.h>

#define NQ 6
#define NL 6
#define TSTRIDE 148   // words per sample trig row: 36 gates * 4 + 4 pad

// R14 = R12 (best: 24.8us; lane^4/8 on DS) + lane^1/lane^2 ALSO moved to the
// DS pipe (ds_swizzle BitMode 0x041F / 0x081F, ISA-doc butterfly patterns).
// R13 showed DS->VALU migration hurts (VALU is the long pole, DS has headroom).
// Masked-DPP conditional CNOT folds stay on VALU (old-operand trick).
// Everything else byte-identical to R12 (validated R8..R13).
// 16 lanes per sample, 4 samples/wave. amplitude k = (b5..b0):
//   b5..b2 <-> L bits 3..0 (L = lane & 15); b1 = pair p; b0 = half h (.x/.y)

typedef float v2f __attribute__((ext_vector_type(2)));

template<int CTRL>
__device__ __forceinline__ float dppf(float x) {
    return __builtin_bit_cast(float,
        __builtin_amdgcn_update_dpp(0, __builtin_bit_cast(int, x), CTRL, 0xF, 0xF, true));
}
// masked conditional DPP: enabled banks get quad_perm<CTRL>(src), others keep old
template<int CTRL, int BANK>
__device__ __forceinline__ float dppsel(float old, float src) {
    return __builtin_bit_cast(float,
        __builtin_amdgcn_update_dpp(__builtin_bit_cast(int, old),
                                    __builtin_bit_cast(int, src),
                                    CTRL, 0xF, BANK, false));
}
// DS-pipe lane xor shuffle (BitMode: offset = (xor<<10) | 0x1F)
template<int OFF>
__device__ __forceinline__ float swzf(float x) {
    return __builtin_bit_cast(float,
        __builtin_amdgcn_ds_swizzle(__builtin_bit_cast(int, x), OFF));
}
__device__ __forceinline__ float sx1(float x) { return swzf<0x041F>(x); }  // lane^1 (DS)
__device__ __forceinline__ float sx2(float x) { return swzf<0x081F>(x); }  // lane^2 (DS)
__device__ __forceinline__ float sx4(float x) { return swzf<0x101F>(x); }  // lane^4 (DS)
__device__ __forceinline__ float sx8(float x) { return swzf<0x201F>(x); }  // lane^8 (DS)

__device__ __forceinline__ v2f fma2(v2f a, v2f b, v2f c) {
    return __builtin_elementwise_fma(a, b, c);
}
__device__ __forceinline__ v2f swap2(v2f a) { return __builtin_shufflevector(a, a, 1, 0); }

template<int M>
__device__ __forceinline__ v2f shuf2(v2f a) {
    if constexpr (M == 1) return v2f{sx1(a.x), sx1(a.y)};
    else if constexpr (M == 2) return v2f{sx2(a.x), sx2(a.y)};
    else if constexpr (M == 4) return v2f{sx4(a.x), sx4(a.y)};
    else return v2f{sx8(a.x), sx8(a.y)};
}

// ---- RZ(q): diagonal, no communication ----
template<int Q>
__device__ __forceinline__ void rz2(v2f (&re)[2], v2f (&im)[2], float c, float s, int L) {
    const v2f C = {c, c};
    if constexpr (Q < 4) {
        const int lm = 8 >> Q;
        const float s2 = (L & lm) ? s : -s;
        const v2f S = {s2, s2};
        #pragma unroll
        for (int p = 0; p < 2; ++p) {
            const v2f nr = fma2(re[p], C, -(im[p] * S));
            im[p] = fma2(re[p], S, im[p] * C);
            re[p] = nr;
        }
    } else if constexpr (Q == 4) {
        const v2f Sn = {-s, -s}, Sp = {s, s};
        { const v2f nr = fma2(re[0], C, -(im[0] * Sn));
          im[0] = fma2(re[0], Sn, im[0] * C); re[0] = nr; }
        { const v2f nr = fma2(re[1], C, -(im[1] * Sp));
          im[1] = fma2(re[1], Sp, im[1] * C); re[1] = nr; }
    } else {
        const v2f S = {-s, s};
        #pragma unroll
        for (int p = 0; p < 2; ++p) {
            const v2f nr = fma2(re[p], C, -(im[p] * S));
            im[p] = fma2(re[p], S, im[p] * C);
            re[p] = nr;
        }
    }
}

// ---- RY(q) ----
template<int Q>
__device__ __forceinline__ void ry2(v2f (&re)[2], v2f (&im)[2], float c, float s, int L) {
    const v2f C = {c, c};
    if constexpr (Q < 4) {
        const int lm = 8 >> Q;
        const float sg = (L & lm) ? s : -s;
        const v2f SG = {sg, sg};
        #pragma unroll
        for (int p = 0; p < 2; ++p) {
            const v2f ore = shuf2<(8 >> Q)>(re[p]);
            const v2f oim = shuf2<(8 >> Q)>(im[p]);
            re[p] = fma2(C, re[p], SG * ore);
            im[p] = fma2(C, im[p], SG * oim);
        }
    } else if constexpr (Q == 4) {
        const v2f S = {s, s};
        const v2f a0r = re[0], a0i = im[0], a1r = re[1], a1i = im[1];
        re[0] = fma2(C, a0r, -(S * a1r));
        im[0] = fma2(C, a0i, -(S * a1i));
        re[1] = fma2(S, a0r, C * a1r);
        im[1] = fma2(S, a0i, C * a1i);
    } else {
        const v2f SM = {-s, s};
        #pragma unroll
        for (int p = 0; p < 2; ++p) {
            re[p] = fma2(C, re[p], SM * swap2(re[p]));
            im[p] = fma2(C, im[p], SM * swap2(im[p]));
        }
    }
}

__device__ __forceinline__ void cnot_block(v2f (&re)[2], v2f (&im)[2], int L) {
    // CNOT(0,1): ctrl b5 (L&8 -> banks 2,3). tgt b4 (lane^4 = xor7 o xor3).
    // Stage1 (xor7) all lanes; stage2 (quad_perm 0x1B = xor3) masked to banks 2,3
    // with old = original value -> conditional move. (VALU, validated R11/R12)
    #pragma unroll
    for (int p = 0; p < 2; ++p) {
        const float t0 = dppf<0x141>(re[p].x), t1 = dppf<0x141>(re[p].y);
        const float u0 = dppf<0x141>(im[p].x), u1 = dppf<0x141>(im[p].y);
        re[p].x = dppsel<0x1B, 0xC>(re[p].x, t0);
        re[p].y = dppsel<0x1B, 0xC>(re[p].y, t1);
        im[p].x = dppsel<0x1B, 0xC>(im[p].x, u0);
        im[p].y = dppsel<0x1B, 0xC>(im[p].y, u1);
    }
    // CNOT(1,2): ctrl b4 (L&4 -> banks 1,3), tgt b3 (lane^2 = quad_perm 0x4E).
    #pragma unroll
    for (int p = 0; p < 2; ++p) {
        re[p].x = dppsel<0x4E, 0xA>(re[p].x, re[p].x);
        re[p].y = dppsel<0x4E, 0xA>(re[p].y, re[p].y);
        im[p].x = dppsel<0x4E, 0xA>(im[p].x, im[p].x);
        im[p].y = dppsel<0x4E, 0xA>(im[p].y, im[p].y);
    }
    // CNOT(2,3): ctrl b3 (L&2), tgt b2 (lane^1): quad_perm [0,1,3,2] = 0xB4
    #pragma unroll
    for (int p = 0; p < 2; ++p) {
        re[p].x = dppf<0xB4>(re[p].x);
        re[p].y = dppf<0xB4>(re[p].y);
        im[p].x = dppf<0xB4>(im[p].x);
        im[p].y = dppf<0xB4>(im[p].y);
    }
    // CNOT(3,4): ctrl b2 (L&1), tgt b1: conditional pair swap
    const bool c34 = (L & 1) != 0;
    {
        const v2f ar = re[0], ai = im[0], br = re[1], bi = im[1];
        re[0] = c34 ? br : ar;  im[0] = c34 ? bi : ai;
        re[1] = c34 ? ar : br;  im[1] = c34 ? ai : bi;
    }
    // CNOT(4,5): ctrl b1 (pair 1), tgt b0: unconditional half-swap of pair 1
    re[1] = swap2(re[1]);  im[1] = swap2(im[1]);
    // CNOT(5,0): ctrl b0 (.y halves), tgt b5: lane^8 on .y only (DS pipe)
    #pragma unroll
    for (int p = 0; p < 2; ++p) {
        re[p].y = sx8(re[p].y);
        im[p].y = sx8(im[p].y);
    }
}

__global__ __launch_bounds__(256, 8) void qsim_kernel(
    const float* __restrict__ x,
    const float* __restrict__ w,
    float* __restrict__ out,
    int batch)
{
    __shared__ float tbl[16 * TSTRIDE];
    __shared__ float outbuf[4][24];

    const int tid   = threadIdx.x;
    const int wavei = tid >> 6;
    const int lane  = tid & 63;
    const int L     = lane & 15;          // position within sample
    const int sw    = lane >> 4;          // sample within wave 0..3
    const int S     = tid >> 4;           // sample within block 0..15
    const int b     = blockIdx.x * 16 + S;
    if (b >= batch) return;               // exact for B=32768 (never divergent)

    float* T = &tbl[S * TSTRIDE];

    // ---- wave-local trig fill: 72 angles/sample, <=5 per lane ----
    {
        const float* wp = w + (size_t)b * (2 * NQ * NL);
        #pragma unroll
        for (int j = 0; j < 5; ++j) {
            const int A = L + 16 * j;                     // angle id
            if (A < 72) {
                float s, c;
                __sincosf(wp[A] * 0.5f, &s, &c);
                const int word = (A >> 1) * 4 + (A & 1) * 2;  // gate*4 + {0:z,2:y}
                T[word]     = c;
                T[word + 1] = s;
            }
        }
    }

    // ---- encode angles via half-angle identities (4 live scalars) ----
    const float x0 = x[b * 3 + 0];
    const float x1 = x[b * 3 + 1];
    const float x2 = x[b * 3 + 2];
    const float z  = fminf(1.f, fmaxf(-1.f, x2));
    const float ct = sqrtf(0.5f * (1.f + z));             // cos(theta/2)
    const float st = sqrtf(0.5f * (1.f - z));             // sin(theta/2)
    const float rr = sqrtf(x0 * x0 + x1 * x1) + 1e-30f;
    const float cphi = x0 / rr;
    const float cp = sqrtf(fmaxf(0.f, 0.5f * (1.f + cphi)));
    float sp       = sqrtf(fmaxf(0.f, 0.5f * (1.f - cphi)));
    sp = (x1 < 0.f) ? -sp : sp;   // 2pi wrap & sign = global phase, cancels

    // ---- |0...0> then gate-based encode: RY(theta), RZ(phi) per qubit ----
    v2f re[2], im[2];
    re[0] = v2f{(L == 0) ? 1.f : 0.f, 0.f};
    re[1] = v2f{0.f, 0.f};
    im[0] = v2f{0.f, 0.f};
    im[1] = v2f{0.f, 0.f};

    ry2<0>(re, im, ct, st, L);  rz2<0>(re, im, cp, sp, L);
    ry2<1>(re, im, ct, st, L);  rz2<1>(re, im, cp, sp, L);
    ry2<2>(re, im, ct, st, L);  rz2<2>(re, im, cp, sp, L);
    ry2<3>(re, im, ct, st, L);  rz2<3>(re, im, cp, sp, L);
    ry2<4>(re, im, ct, st, L);  rz2<4>(re, im, cp, sp, L);
    ry2<5>(re, im, ct, st, L);  rz2<5>(re, im, cp, sp, L);

    // ---- variational layers: rolled loop (R10-validated) ----
    #pragma unroll 1
    for (int l = 0; l < NL; ++l) {
        const float* Tl = &T[l * 24];
        const float4 c0 = *(const float4*)&Tl[ 0];
        const float4 c1 = *(const float4*)&Tl[ 4];
        const float4 c2 = *(const float4*)&Tl[ 8];
        const float4 c3 = *(const float4*)&Tl[12];
        const float4 c4 = *(const float4*)&Tl[16];
        const float4 c5 = *(const float4*)&Tl[20];
        rz2<0>(re, im, c0.x, c0.y, L);  ry2<0>(re, im, c0.z, c0.w, L);
        rz2<1>(re, im, c1.x, c1.y, L);  ry2<1>(re, im, c1.z, c1.w, L);
        rz2<2>(re, im, c2.x, c2.y, L);  ry2<2>(re, im, c2.z, c2.w, L);
        rz2<3>(re, im, c3.x, c3.y, L);  ry2<3>(re, im, c3.z, c3.w, L);
        rz2<4>(re, im, c4.x, c4.y, L);  ry2<4>(re, im, c4.z, c4.w, L);
        rz2<5>(re, im, c5.x, c5.y, L);  ry2<5>(re, im, c5.z, c5.w, L);
        if (l < NL - 1) cnot_block(re, im, L);   // uniform branch
    }
    // final CNOT block folded into readout remap (validated R3..R13)

    // ---- probs -> FWHT (2 register stages + 4 lane stages) ----
    v2f v[2];
    v[0] = fma2(re[0], re[0], im[0] * im[0]);
    v[1] = fma2(re[1], re[1], im[1] * im[1]);
    {   // amp bit1 (pair)
        const v2f a = v[0], bb = v[1];
        v[0] = a + bb; v[1] = a - bb;
    }
    {   // amp bit0 (half)
        const v2f PM = {1.f, -1.f};
        v[0] = fma2(PM, v[0], swap2(v[0]));
        v[1] = fma2(PM, v[1], swap2(v[1]));
    }
    {   // amp bit2 <-> L bit0 (DS)
        const float sg = (L & 1) ? -1.f : 1.f;  const v2f SG = {sg, sg};
        v[0] = fma2(SG, v[0], shuf2<1>(v[0]));
        v[1] = fma2(SG, v[1], shuf2<1>(v[1]));
    }
    {   // amp bit3 <-> L bit1 (DS)
        const float sg = (L & 2) ? -1.f : 1.f;  const v2f SG = {sg, sg};
        v[0] = fma2(SG, v[0], shuf2<2>(v[0]));
        v[1] = fma2(SG, v[1], shuf2<2>(v[1]));
    }
    {   // amp bit4 <-> L bit2 (DS)
        const float sg = (L & 4) ? -1.f : 1.f;  const v2f SG = {sg, sg};
        v[0] = fma2(SG, v[0], shuf2<4>(v[0]));
        v[1] = fma2(SG, v[1], shuf2<4>(v[1]));
    }
    {   // amp bit5 <-> L bit3 (DS)
        const float sg = (L & 8) ? -1.f : 1.f;  const v2f SG = {sg, sg};
        v[0] = fma2(SG, v[0], shuf2<8>(v[0]));
        v[1] = fma2(SG, v[1], shuf2<8>(v[1]));
    }
    // lane L, pair p, half h holds WHT[L*4 + 2p + h]

    // ---- readout (skipped final-CNOT remap, validated): e = {31,48,56,60,62,63} ----
    if (L == 7)  outbuf[wavei][sw * 6 + 0] = v[1].y;   // e=31
    if (L == 12) outbuf[wavei][sw * 6 + 1] = v[0].x;   // e=48
    if (L == 14) outbuf[wavei][sw * 6 + 2] = v[0].x;   // e=56
    if (L == 15) {
        outbuf[wavei][sw * 6 + 3] = v[0].x;            // e=60
        outbuf[wavei][sw * 6 + 4] = v[1].x;            // e=62
        outbuf[wavei][sw * 6 + 5] = v[1].y;            // e=63
    }
    if (lane < 24) {
        const float ev = outbuf[wavei][lane];
        const long long oidx = (long long)(blockIdx.x * 16 + wavei * 4) * 6 + lane;
        if (oidx < (long long)batch * 6)
            out[oidx] = 1.f / (1.f + __expf(-ev));
    }
}

extern "C" void kernel_launch(void* const* d_in, const int* in_sizes, int n_in,
                              void* d_out, int out_size, void* d_ws, size_t ws_size,
                              hipStream_t stream) {
    const float* x = (const float*)d_in[0];
    const float* w = (const float*)d_in[1];
    float* out = (float*)d_out;
    const int batch = in_sizes[0] / 3;   // B = 32768

    const int threads = 256;             // 4 waves = 16 samples per block
    const int blocks = (batch + 15) / 16;
    qsim_kernel<<<blocks, threads, 0, stream>>>(x, w, out, batch);
}